// Round 3
// baseline (232.752 us; speedup 1.0000x reference)
//
#include <hip/hip_runtime.h>

namespace {

constexpr int C = 64, H = 128, W = 128, HK = 640, WK = 640;
constexpr long long CSTR = (long long)HK * WK;   // channel stride in fkv
constexpr int THREADS = 512;

__device__ inline unsigned int packbf2(float lo, float hi) {
    unsigned int a = __float_as_uint(lo), b = __float_as_uint(hi);
    a = (a + 0x7FFFu + ((a >> 16) & 1u)) >> 16;          // RNE f32->bf16
    b = (b + 0x7FFFu + ((b >> 16) & 1u)) & 0xFFFF0000u;
    return a | b;
}
__device__ inline float blo(unsigned int u) { return __uint_as_float(u << 16); }
__device__ inline float bhi(unsigned int u) { return __uint_as_float(u & 0xFFFF0000u); }

// ---------------- prep: Wqk = 0.125 * Wk^T Wq ----------------
__global__ void prep_wqk(const float* __restrict__ Wq, const float* __restrict__ Wk,
                         float* __restrict__ Wqk) {
    int tid = blockIdx.x * 256 + threadIdx.x;    // 4096 = 64*64
    int i = tid >> 6, j = tid & 63;
    float acc = 0.f;
    #pragma unroll 8
    for (int c = 0; c < 64; ++c) acc = fmaf(Wk[c * 64 + i], Wq[c * 64 + j], acc);
    Wqk[i * 64 + j] = 0.125f * acc;
}

// ---------------- qk-proj: qk[pix][slot] (packed bf16, natural pair order) ----
// thread = one pixel; fq column reads coalesced across lanes.
__global__ __launch_bounds__(256)
void qk_proj(const float* __restrict__ fq, const float* __restrict__ Wqk,
             unsigned int* __restrict__ qk_g) {
    const int pix = blockIdx.x * 256 + threadIdx.x;      // 0..65535
    const int b = pix >> 14, l = pix & 16383;
    float col[64];
    #pragma unroll
    for (int c = 0; c < 64; ++c)
        col[c] = fq[((size_t)(b * 64 + c) << 14) + l];
    #pragma unroll 2
    for (int i4 = 0; i4 < 16; ++i4) {                    // channels 4*i4 .. +3
        float a0 = 0.f, a1 = 0.f, a2 = 0.f, a3 = 0.f;
        #pragma unroll
        for (int j = 0; j < 64; ++j) {
            float f = col[j];
            a0 = fmaf(Wqk[(4 * i4 + 0) * 64 + j], f, a0);
            a1 = fmaf(Wqk[(4 * i4 + 1) * 64 + j], f, a1);
            a2 = fmaf(Wqk[(4 * i4 + 2) * 64 + j], f, a2);
            a3 = fmaf(Wqk[(4 * i4 + 3) * 64 + j], f, a3);
        }
        uint2 u = make_uint2(packbf2(a0, a1), packbf2(a2, a3));
        *(uint2*)&qk_g[(size_t)pix * 32 + 2 * i4] = u;
    }
}

// ---------------- main: stage slab, logits, softmax, wsum ----------------
// slab layout: [(y*80 + x)*32 + (slot ^ swz(x,y))], slot s <-> channels
// (4*(s>>1)+2*(s&1), +1).  swz = ((x&7)^y)<<2 keeps b128 granules contiguous.
__global__ __launch_bounds__(THREADS, 6)
void cag_attn(const float* __restrict__ fkv, const unsigned int* __restrict__ qk_g,
              unsigned int* __restrict__ wsum_g) {
    __shared__ unsigned int slab[5 * 80 * 32];           // 51200 B
    __shared__ float lg[16 * 26];                        // 1664 B

    const int t = threadIdx.x;
    const int bid = blockIdx.x;
    const int wb = bid & 7;
    const int h  = (bid >> 3) & 127;
    const int b  = bid >> 10;
    const int row0 = 5 * h, col0 = 80 * wb;
    const int pix0 = h * 128 + 16 * wb;                  // local pixel base

    // ---- stage: lanes = (x4s:4 fastest, c4:16); (y,x4g) wave-uniform ----
    {
        const float* kvb = fkv + (size_t)b * C * CSTR;
        for (int i = t; i < 1600; i += THREADS) {
            const int x4s = i & 3;
            const int c4  = (i >> 2) & 15;
            const int rem = i >> 6;                      // 0..24
            const int y   = rem % 5;
            const int x4g = rem / 5;
            const int xb  = 16 * x4g + 4 * x4s;          // local x of float4
            const float* g = kvb + (size_t)(4 * c4) * CSTR
                           + (size_t)(row0 + y) * WK + (col0 + xb);
            float4 F0 = *(const float4*)(g);
            float4 F1 = *(const float4*)(g + CSTR);
            float4 F2 = *(const float4*)(g + 2 * CSTR);
            float4 F3 = *(const float4*)(g + 3 * CSTR);
            const float* f0 = (const float*)&F0; const float* f1 = (const float*)&F1;
            const float* f2 = (const float*)&F2; const float* f3 = (const float*)&F3;
            #pragma unroll
            for (int dx = 0; dx < 4; ++dx) {
                const int x = xb + dx;
                const int base = (y * 80 + x) * 32;
                const int sw = (((x & 7) ^ y) << 2);
                slab[base + ((2 * c4)     ^ sw)] = packbf2(f0[dx], f1[dx]);
                slab[base + ((2 * c4 + 1) ^ sw)] = packbf2(f2[dx], f3[dx]);
            }
        }
    }
    __syncthreads();

    const int l = t >> 5;          // pixel 0..15
    const int n = t & 31;          // kv position 0..24 (25..31 idle)

    // ---- logits + in-wave softmax (32-lane groups, one l per group) ----
    {
        float v = -1e30f;
        if (n < 25) {
            const int ky = n / 5, kx = n - 5 * (n / 5);
            const int x = 5 * l + kx;
            const int base = (ky * 80 + x) * 32;
            const int sw7 = (x & 7) ^ ky;
            const uint4* qkr = (const uint4*)(qk_g + ((size_t)b * 16384 + pix0 + l) * 32);
            float acc = 0.f;
            #pragma unroll
            for (int j = 0; j < 8; ++j) {
                uint4 u = *(const uint4*)&slab[base + 4 * (j ^ sw7)];
                uint4 q = qkr[j];
                acc = fmaf(blo(q.x), blo(u.x), acc); acc = fmaf(bhi(q.x), bhi(u.x), acc);
                acc = fmaf(blo(q.y), blo(u.y), acc); acc = fmaf(bhi(q.y), bhi(u.y), acc);
                acc = fmaf(blo(q.z), blo(u.z), acc); acc = fmaf(bhi(q.z), bhi(u.z), acc);
                acc = fmaf(blo(q.w), blo(u.w), acc); acc = fmaf(bhi(q.w), bhi(u.w), acc);
            }
            v = acc;
        }
        float m = v;
        #pragma unroll
        for (int off = 16; off; off >>= 1) m = fmaxf(m, __shfl_xor(m, off, 32));
        float e = __expf(v - m);
        float s = e;
        #pragma unroll
        for (int off = 16; off; off >>= 1) s += __shfl_xor(s, off, 32);
        if (n < 25) lg[l * 26 + n] = e / s;
    }
    __syncthreads();

    // ---- wsum[l][slot] = sum_n a[l][n] * slab[n][slot];  write bf16-packed ----
    {
        const int s = t & 31;      // slot
        float alo = 0.f, ahi = 0.f;
        #pragma unroll
        for (int n2 = 0; n2 < 25; ++n2) {
            const int ky = n2 / 5, kx = n2 - 5 * ky;     // compile-time
            const int x = 5 * l + kx;
            const unsigned int u = slab[(ky * 80 + x) * 32 + (s ^ ((((x & 7) ^ ky)) << 2))];
            const float a = lg[l * 26 + n2];
            alo = fmaf(a, blo(u), alo);
            ahi = fmaf(a, bhi(u), ahi);
        }
        wsum_g[((size_t)b * 16384 + pix0 + l) * 32 + s] = packbf2(alo, ahi);
    }
}

// ---------------- out-proj: out = fq + Wv @ wsum ----------------
// thread = one pixel; unpacks slab slot order -> channel order.
__global__ __launch_bounds__(256)
void out_proj(const float* __restrict__ fq, const float* __restrict__ Wv,
              const unsigned int* __restrict__ wsum_g, float* __restrict__ out) {
    const int pix = blockIdx.x * 256 + threadIdx.x;
    const int b = pix >> 14, l = pix & 16383;
    float vals[64];
    #pragma unroll
    for (int g8 = 0; g8 < 8; ++g8) {
        uint4 u = *(const uint4*)&wsum_g[(size_t)pix * 32 + 4 * g8];
        const unsigned int us[4] = {u.x, u.y, u.z, u.w};
        #pragma unroll
        for (int c2 = 0; c2 < 4; ++c2) {
            const int s = 4 * g8 + c2;
            const int ic0 = 4 * (s >> 1) + 2 * (s & 1);
            vals[ic0]     = blo(us[c2]);
            vals[ic0 + 1] = bhi(us[c2]);
        }
    }
    #pragma unroll 2
    for (int oc = 0; oc < 64; ++oc) {
        float acc = fq[((size_t)(b * 64 + oc) << 14) + l];
        #pragma unroll
        for (int ic = 0; ic < 64; ++ic)
            acc = fmaf(Wv[oc * 64 + ic], vals[ic], acc);
        out[((size_t)(b * 64 + oc) << 14) + l] = acc;
    }
}

} // namespace

extern "C" void kernel_launch(void* const* d_in, const int* in_sizes, int n_in,
                              void* d_out, int out_size, void* d_ws, size_t ws_size,
                              hipStream_t stream) {
    (void)in_sizes; (void)n_in; (void)ws_size; (void)out_size;
    const float* fq  = (const float*)d_in[0];
    const float* fkv = (const float*)d_in[1];
    const float* Wq  = (const float*)d_in[2];
    const float* Wk  = (const float*)d_in[3];
    const float* Wv  = (const float*)d_in[4];
    float* out = (float*)d_out;

    // workspace layout (byte offsets): Wqk f32 @0 (16KB), qk u32 @16384 (8MB),
    // wsum u32 @16384+8388608 (8MB)
    float* Wqk = (float*)d_ws;
    unsigned int* qk_g   = (unsigned int*)((char*)d_ws + 16384);
    unsigned int* wsum_g = (unsigned int*)((char*)d_ws + 16384 + 8388608);

    prep_wqk<<<dim3(16),   dim3(256), 0, stream>>>(Wq, Wk, Wqk);
    qk_proj <<<dim3(256),  dim3(256), 0, stream>>>(fq, Wqk, qk_g);
    cag_attn<<<dim3(4096), dim3(THREADS), 0, stream>>>(fkv, qk_g, wsum_g);
    out_proj<<<dim3(256),  dim3(256), 0, stream>>>(fq, Wv, wsum_g, out);
}

// Round 4
// 159.248 us; speedup vs baseline: 1.4616x; 1.4616x over previous
//
#include <hip/hip_runtime.h>
#include <hip/hip_bf16.h>

namespace {

constexpr int C = 64, H = 128, W = 128, HK = 640, WK = 640;
constexpr long long CSTR = (long long)HK * WK;   // channel stride in fkv
constexpr int THREADS = 512;

__device__ inline unsigned int packbf2(float lo, float hi) {
    __hip_bfloat162 h2 = __float22bfloat162_rn(make_float2(lo, hi));  // v_cvt_pk_bf16_f32
    return *reinterpret_cast<unsigned int*>(&h2);
}
__device__ inline float blo(unsigned int u) { return __uint_as_float(u << 16); }
__device__ inline float bhi(unsigned int u) { return __uint_as_float(u & 0xFFFF0000u); }

// ---------------- prep: Wqk = 0.125 * Wk^T Wq  (16 KB scratch) ----------------
__global__ void prep_wqk(const float* __restrict__ Wq, const float* __restrict__ Wk,
                         float* __restrict__ Wqk) {
    int tid = blockIdx.x * 256 + threadIdx.x;    // 4096 = 64*64
    int i = tid >> 6, j = tid & 63;
    float acc = 0.f;
    #pragma unroll 8
    for (int c = 0; c < 64; ++c) acc = fmaf(Wk[c * 64 + i], Wq[c * 64 + j], acc);
    Wqk[i * 64 + j] = 0.125f * acc;
}

// ---------------- fused main ----------------
// slab layout: [(y*80 + x)*32 + (slot ^ swz)], swz = ((x&7)^y)<<2.
// slot s holds channels ic0 = 4*(s>>1)+2*(s&1) (lo) and ic0+1 (hi); granule
// j (slots 4j..4j+3) = channels 8j..8j+7 in order.
__global__ __launch_bounds__(THREADS, 4)
void cag_fused(const float* __restrict__ fq, const float* __restrict__ fkv,
               const float* __restrict__ Wqk, const float* __restrict__ Wv,
               float* __restrict__ out) {
    __shared__ unsigned int slab[5 * 80 * 32];       // 51200 B, bf16 pairs
    __shared__ float fq_lds[16 * 68];                //  4352 B  [p][c]
    __shared__ float qk_lds[16 * 68];                //  4352 B  [l][ic] f32
    __shared__ float lg[16 * 26];                    //  1664 B
    __shared__ unsigned int wsum[16 * 36];           //  2304 B  [l][slot] (pad 36)

    const int t = threadIdx.x;
    const int bid = blockIdx.x;
    const int wb = bid & 7;
    const int h  = (bid >> 3) & 127;
    const int b  = bid >> 10;
    const int row0 = 5 * h, col0 = 80 * wb, w0q = 16 * wb;

    // ---- stage fq tile [p][c] (coalesced) ----
    {
        const int p = t & 15, c = t >> 4;            // c in 0..31
        fq_lds[p * 68 + c]      = fq[((size_t)(b * 64 + c) << 14) + h * 128 + w0q + p];
        fq_lds[p * 68 + c + 32] = fq[((size_t)(b * 64 + c + 32) << 14) + h * 128 + w0q + p];
    }
    // ---- stage kv slab: f32 -> packed bf16, channel-major swizzled ----
    {
        const float* kvb = fkv + (size_t)b * C * CSTR;
        for (int i = t; i < 1600; i += THREADS) {    // 4 x4s * 16 c4 * 25 (y,x4g)
            const int x4s = i & 3;
            const int c4  = (i >> 2) & 15;
            const int rem = i >> 6;                  // 0..24
            const int y   = rem % 5;
            const int x4g = rem / 5;
            const int xb  = 16 * x4g + 4 * x4s;
            const float* g = kvb + (size_t)(4 * c4) * CSTR
                           + (size_t)(row0 + y) * WK + (col0 + xb);
            float4 F0 = *(const float4*)(g);
            float4 F1 = *(const float4*)(g + CSTR);
            float4 F2 = *(const float4*)(g + 2 * CSTR);
            float4 F3 = *(const float4*)(g + 3 * CSTR);
            const float* f0 = (const float*)&F0; const float* f1 = (const float*)&F1;
            const float* f2 = (const float*)&F2; const float* f3 = (const float*)&F3;
            #pragma unroll
            for (int dx = 0; dx < 4; ++dx) {
                const int x = xb + dx;
                const int base = (y * 80 + x) * 32;
                const int sw = (((x & 7) ^ y) << 2);
                slab[base + ((2 * c4)     ^ sw)] = packbf2(f0[dx], f1[dx]);
                slab[base + ((2 * c4 + 1) ^ sw)] = packbf2(f2[dx], f3[dx]);
            }
        }
    }
    __syncthreads();

    // ---- qk[l][i] = sum_j Wqk[i][j] * fq_lds[l][j]  (f32) ----
    {
        const int l = t & 15, i0 = t >> 4;           // i0 in 0..31
        const float4* wr0 = (const float4*)(Wqk + i0 * 64);
        const float4* wr1 = (const float4*)(Wqk + (i0 + 32) * 64);
        const float4* fv  = (const float4*)(fq_lds + l * 68);
        float a0 = 0.f, a1 = 0.f;
        #pragma unroll
        for (int j = 0; j < 16; ++j) {
            float4 f = fv[j], w0 = wr0[j], w1 = wr1[j];
            a0 = fmaf(w0.x, f.x, a0); a0 = fmaf(w0.y, f.y, a0);
            a0 = fmaf(w0.z, f.z, a0); a0 = fmaf(w0.w, f.w, a0);
            a1 = fmaf(w1.x, f.x, a1); a1 = fmaf(w1.y, f.y, a1);
            a1 = fmaf(w1.z, f.z, a1); a1 = fmaf(w1.w, f.w, a1);
        }
        qk_lds[l * 68 + i0]      = a0;
        qk_lds[l * 68 + i0 + 32] = a1;
    }
    __syncthreads();

    // ---- logits (8x ds_read_b128, conflict-free) + in-wave softmax ----
    {
        const int l = t >> 5;        // pixel 0..15 (one per 32-lane group)
        const int n = t & 31;        // kv position 0..24
        float v = -1e30f;
        if (n < 25) {
            const int ky = n / 5, kx = n - 5 * (n / 5);
            const int x = 5 * l + kx;
            const int base = (ky * 80 + x) * 32;
            const int sw7 = (x & 7) ^ ky;
            const float4* qv = (const float4*)(qk_lds + l * 68);
            float acc = 0.f;
            #pragma unroll
            for (int j = 0; j < 8; ++j) {
                uint4 u = *(const uint4*)&slab[base + 4 * (j ^ sw7)];
                float4 qa = qv[2 * j], qb = qv[2 * j + 1];
                acc = fmaf(qa.x, blo(u.x), acc); acc = fmaf(qa.y, bhi(u.x), acc);
                acc = fmaf(qa.z, blo(u.y), acc); acc = fmaf(qa.w, bhi(u.y), acc);
                acc = fmaf(qb.x, blo(u.z), acc); acc = fmaf(qb.y, bhi(u.z), acc);
                acc = fmaf(qb.z, blo(u.w), acc); acc = fmaf(qb.w, bhi(u.w), acc);
            }
            v = acc;
        }
        float m = v;
        #pragma unroll
        for (int off = 16; off; off >>= 1) m = fmaxf(m, __shfl_xor(m, off, 32));
        float e = __expf(v - m);
        float s = e;
        #pragma unroll
        for (int off = 16; off; off >>= 1) s += __shfl_xor(s, off, 32);
        if (n < 25) lg[l * 26 + n] = e / s;
    }
    __syncthreads();

    // ---- wsum[l][slot] = sum_n a[l][n] * slab[n][slot]  (bank-permutation reads) ----
    {
        const int l = t >> 5, s = t & 31;
        float alo = 0.f, ahi = 0.f;
        #pragma unroll
        for (int n2 = 0; n2 < 25; ++n2) {
            const int ky = n2 / 5, kx = n2 - 5 * ky;         // compile-time
            const int x = 5 * l + kx;
            const unsigned int u = slab[(ky * 80 + x) * 32 + (s ^ ((((x & 7) ^ ky)) << 2))];
            const float a = lg[l * 26 + n2];
            alo = fmaf(a, blo(u), alo);
            ahi = fmaf(a, bhi(u), ahi);
        }
        wsum[l * 36 + s] = packbf2(alo, ahi);
    }
    __syncthreads();

    // ---- out[oc][p] = fq[oc][p] + sum_ic Wv[oc][ic] * wsum[p][ic] ----
    {
        const int p = t & 15, o0 = t >> 4;           // o0 in 0..31
        const uint4* wsr = (const uint4*)(wsum + p * 36);
        float vals[64];
        #pragma unroll
        for (int g8 = 0; g8 < 8; ++g8) {
            uint4 u = wsr[g8];
            vals[8 * g8 + 0] = blo(u.x); vals[8 * g8 + 1] = bhi(u.x);
            vals[8 * g8 + 2] = blo(u.y); vals[8 * g8 + 3] = bhi(u.y);
            vals[8 * g8 + 4] = blo(u.z); vals[8 * g8 + 5] = bhi(u.z);
            vals[8 * g8 + 6] = blo(u.w); vals[8 * g8 + 7] = bhi(u.w);
        }
        const float4* wv0 = (const float4*)(Wv + o0 * 64);
        const float4* wv1 = (const float4*)(Wv + (o0 + 32) * 64);
        float a0 = fq_lds[p * 68 + o0];              // residual
        float a1 = fq_lds[p * 68 + o0 + 32];
        #pragma unroll
        for (int j = 0; j < 16; ++j) {
            float4 w0 = wv0[j], w1 = wv1[j];
            a0 = fmaf(w0.x, vals[4 * j + 0], a0); a0 = fmaf(w0.y, vals[4 * j + 1], a0);
            a0 = fmaf(w0.z, vals[4 * j + 2], a0); a0 = fmaf(w0.w, vals[4 * j + 3], a0);
            a1 = fmaf(w1.x, vals[4 * j + 0], a1); a1 = fmaf(w1.y, vals[4 * j + 1], a1);
            a1 = fmaf(w1.z, vals[4 * j + 2], a1); a1 = fmaf(w1.w, vals[4 * j + 3], a1);
        }
        const size_t ob = ((size_t)(b * 64 + o0) << 14) + h * 128 + w0q + p;
        out[ob] = a0;
        out[ob + ((size_t)32 << 14)] = a1;
    }
}

} // namespace

extern "C" void kernel_launch(void* const* d_in, const int* in_sizes, int n_in,
                              void* d_out, int out_size, void* d_ws, size_t ws_size,
                              hipStream_t stream) {
    (void)in_sizes; (void)n_in; (void)ws_size; (void)out_size;
    const float* fq  = (const float*)d_in[0];
    const float* fkv = (const float*)d_in[1];
    const float* Wq  = (const float*)d_in[2];
    const float* Wk  = (const float*)d_in[3];
    const float* Wv  = (const float*)d_in[4];
    float* out = (float*)d_out;
    float* Wqk = (float*)d_ws;                      // 16 KB scratch

    prep_wqk <<<dim3(16),   dim3(256),     0, stream>>>(Wq, Wk, Wqk);
    cag_fused<<<dim3(4096), dim3(THREADS), 0, stream>>>(fq, fkv, Wqk, Wv, out);
}

// Round 5
// 157.142 us; speedup vs baseline: 1.4812x; 1.0134x over previous
//
#include <hip/hip_runtime.h>
#include <hip/hip_bf16.h>

namespace {

constexpr int C = 64, H = 128, W = 128, HK = 640, WK = 640;
constexpr long long CSTR = (long long)HK * WK;   // channel stride in fkv
constexpr int PIX = 8;            // query pixels per block
constexpr int XD = 5 * PIX;       // 40 kv columns per block
constexpr int THREADS = 256;      // 4 waves

__device__ inline unsigned int packbf2(float lo, float hi) {
    __hip_bfloat162 h2 = __float22bfloat162_rn(make_float2(lo, hi));  // v_cvt_pk_bf16_f32
    return *reinterpret_cast<unsigned int*>(&h2);
}
__device__ inline float blo(unsigned int u) { return __uint_as_float(u << 16); }
__device__ inline float bhi(unsigned int u) { return __uint_as_float(u & 0xFFFF0000u); }

// ---------------- prep: Wqk = 0.125 * Wk^T Wq  (16 KB scratch) ----------------
__global__ void prep_wqk(const float* __restrict__ Wq, const float* __restrict__ Wk,
                         float* __restrict__ Wqk) {
    int tid = blockIdx.x * 256 + threadIdx.x;    // 4096 = 64*64
    int i = tid >> 6, j = tid & 63;
    float acc = 0.f;
    #pragma unroll 8
    for (int c = 0; c < 64; ++c) acc = fmaf(Wk[c * 64 + i], Wq[c * 64 + j], acc);
    Wqk[i * 64 + j] = 0.125f * acc;
}

// ---------------- fused main (PIX=8 tile, 5 blocks/CU) ----------------
// slab layout: [(y*XD + x)*32 + (slot ^ swz)], swz = ((x&7)^y)<<2.
// slot s holds channels ic0 = 4*(s>>1)+2*(s&1) (lo) and ic0+1 (hi).
__global__ __launch_bounds__(THREADS, 5)
void cag_fused(const float* __restrict__ fq, const float* __restrict__ fkv,
               const float* __restrict__ Wqk, const float* __restrict__ Wv,
               float* __restrict__ out) {
    __shared__ unsigned int slab[5 * XD * 32];       // 25600 B, bf16 pairs
    __shared__ float fq_lds[PIX * 68];               //  2176 B  [p][c]
    __shared__ float qk_lds[PIX * 68];               //  2176 B  [l][ic] f32
    __shared__ float lg[PIX * 26];                   //   832 B
    __shared__ unsigned int wsum[PIX * 36];          //  1152 B  [l][slot]

    const int t = threadIdx.x;
    const int bid = blockIdx.x;
    const int wb = bid & 15;                 // W/PIX = 16
    const int h  = (bid >> 4) & 127;
    const int b  = bid >> 11;
    const int row0 = 5 * h, col0 = XD * wb, w0q = PIX * wb;

    // ---- stage fq tile [p][c] ----
    {
        const int p = t & 7, c = t >> 3;     // c in 0..31
        fq_lds[p * 68 + c]      = fq[((size_t)(b * 64 + c) << 14) + h * 128 + w0q + p];
        fq_lds[p * 68 + c + 32] = fq[((size_t)(b * 64 + c + 32) << 14) + h * 128 + w0q + p];
    }
    // ---- stage kv slab: f32 -> packed bf16, channel-major swizzled ----
    {
        const float* kvb = fkv + (size_t)b * C * CSTR;
        for (int i = t; i < 800; i += THREADS) {     // 10 x4 * 5 y * 16 c4
            const int x4 = i % 10;
            const int y  = (i / 10) % 5;
            const int c4 = i / 50;
            const int xb = 4 * x4;
            const float* g = kvb + (size_t)(4 * c4) * CSTR
                           + (size_t)(row0 + y) * WK + (col0 + xb);
            float4 F0 = *(const float4*)(g);
            float4 F1 = *(const float4*)(g + CSTR);
            float4 F2 = *(const float4*)(g + 2 * CSTR);
            float4 F3 = *(const float4*)(g + 3 * CSTR);
            const float* f0 = (const float*)&F0; const float* f1 = (const float*)&F1;
            const float* f2 = (const float*)&F2; const float* f3 = (const float*)&F3;
            #pragma unroll
            for (int dx = 0; dx < 4; ++dx) {
                const int x = xb + dx;
                const int base = (y * XD + x) * 32;
                const int sw = (((x & 7) ^ y) << 2);
                slab[base + ((2 * c4)     ^ sw)] = packbf2(f0[dx], f1[dx]);
                slab[base + ((2 * c4 + 1) ^ sw)] = packbf2(f2[dx], f3[dx]);
            }
        }
    }
    __syncthreads();

    // ---- qk[l][i] = sum_j Wqk[i][j] * fq_lds[l][j]  (f32) ----
    {
        const int l = t & 7, i0 = t >> 3;            // i0 in 0..31
        const float4* wr0 = (const float4*)(Wqk + i0 * 64);
        const float4* wr1 = (const float4*)(Wqk + (i0 + 32) * 64);
        const float4* fv  = (const float4*)(fq_lds + l * 68);
        float a0 = 0.f, a1 = 0.f;
        #pragma unroll
        for (int j = 0; j < 16; ++j) {
            float4 f = fv[j], w0 = wr0[j], w1 = wr1[j];
            a0 = fmaf(w0.x, f.x, a0); a0 = fmaf(w0.y, f.y, a0);
            a0 = fmaf(w0.z, f.z, a0); a0 = fmaf(w0.w, f.w, a0);
            a1 = fmaf(w1.x, f.x, a1); a1 = fmaf(w1.y, f.y, a1);
            a1 = fmaf(w1.z, f.z, a1); a1 = fmaf(w1.w, f.w, a1);
        }
        qk_lds[l * 68 + i0]      = a0;
        qk_lds[l * 68 + i0 + 32] = a1;
    }
    __syncthreads();

    // ---- logits (8x ds_read_b128) + in-wave softmax ----
    {
        const int l = t >> 5;        // pixel 0..7 (one per 32-lane group)
        const int n = t & 31;        // kv position 0..24
        float v = -1e30f;
        if (n < 25) {
            const int ky = n / 5, kx = n - 5 * (n / 5);
            const int x = 5 * l + kx;
            const int base = (ky * XD + x) * 32;
            const int sw7 = (x & 7) ^ ky;
            const float4* qv = (const float4*)(qk_lds + l * 68);
            float acc = 0.f;
            #pragma unroll
            for (int j = 0; j < 8; ++j) {
                uint4 u = *(const uint4*)&slab[base + 4 * (j ^ sw7)];
                float4 qa = qv[2 * j], qb = qv[2 * j + 1];
                acc = fmaf(qa.x, blo(u.x), acc); acc = fmaf(qa.y, bhi(u.x), acc);
                acc = fmaf(qa.z, blo(u.y), acc); acc = fmaf(qa.w, bhi(u.y), acc);
                acc = fmaf(qb.x, blo(u.z), acc); acc = fmaf(qb.y, bhi(u.z), acc);
                acc = fmaf(qb.z, blo(u.w), acc); acc = fmaf(qb.w, bhi(u.w), acc);
            }
            v = acc;
        }
        float m = v;
        #pragma unroll
        for (int off = 16; off; off >>= 1) m = fmaxf(m, __shfl_xor(m, off, 32));
        float e = __expf(v - m);
        float s = e;
        #pragma unroll
        for (int off = 16; off; off >>= 1) s += __shfl_xor(s, off, 32);
        if (n < 25) lg[l * 26 + n] = e / s;
    }
    __syncthreads();

    // ---- wsum[l][slot] = sum_n a[l][n] * slab[n][slot] ----
    {
        const int l = t >> 5, s = t & 31;
        float alo = 0.f, ahi = 0.f;
        #pragma unroll
        for (int n2 = 0; n2 < 25; ++n2) {
            const int ky = n2 / 5, kx = n2 - 5 * ky;         // compile-time
            const int x = 5 * l + kx;
            const unsigned int u = slab[(ky * XD + x) * 32 + (s ^ ((((x & 7) ^ ky)) << 2))];
            const float a = lg[l * 26 + n2];
            alo = fmaf(a, blo(u), alo);
            ahi = fmaf(a, bhi(u), ahi);
        }
        wsum[l * 36 + s] = packbf2(alo, ahi);
    }
    __syncthreads();

    // ---- out[oc][p] = fq[oc][p] + sum_ic Wv[oc][ic] * wsum[p][ic] ----
    {
        const int p = t & 7, o0 = t >> 3;            // o0 in 0..31
        const uint4* wsr = (const uint4*)(wsum + p * 36);
        float vals[64];
        #pragma unroll
        for (int g8 = 0; g8 < 8; ++g8) {
            uint4 u = wsr[g8];
            vals[8 * g8 + 0] = blo(u.x); vals[8 * g8 + 1] = bhi(u.x);
            vals[8 * g8 + 2] = blo(u.y); vals[8 * g8 + 3] = bhi(u.y);
            vals[8 * g8 + 4] = blo(u.z); vals[8 * g8 + 5] = bhi(u.z);
            vals[8 * g8 + 6] = blo(u.w); vals[8 * g8 + 7] = bhi(u.w);
        }
        const float4* wv0 = (const float4*)(Wv + o0 * 64);
        const float4* wv1 = (const float4*)(Wv + (o0 + 32) * 64);
        float a0 = fq_lds[p * 68 + o0];              // residual
        float a1 = fq_lds[p * 68 + o0 + 32];
        #pragma unroll
        for (int j = 0; j < 16; ++j) {
            float4 w0 = wv0[j], w1 = wv1[j];
            a0 = fmaf(w0.x, vals[4 * j + 0], a0); a0 = fmaf(w0.y, vals[4 * j + 1], a0);
            a0 = fmaf(w0.z, vals[4 * j + 2], a0); a0 = fmaf(w0.w, vals[4 * j + 3], a0);
            a1 = fmaf(w1.x, vals[4 * j + 0], a1); a1 = fmaf(w1.y, vals[4 * j + 1], a1);
            a1 = fmaf(w1.z, vals[4 * j + 2], a1); a1 = fmaf(w1.w, vals[4 * j + 3], a1);
        }
        const size_t ob = ((size_t)(b * 64 + o0) << 14) + h * 128 + w0q + p;
        out[ob] = a0;
        out[ob + ((size_t)32 << 14)] = a1;
    }
}

} // namespace

extern "C" void kernel_launch(void* const* d_in, const int* in_sizes, int n_in,
                              void* d_out, int out_size, void* d_ws, size_t ws_size,
                              hipStream_t stream) {
    (void)in_sizes; (void)n_in; (void)ws_size; (void)out_size;
    const float* fq  = (const float*)d_in[0];
    const float* fkv = (const float*)d_in[1];
    const float* Wq  = (const float*)d_in[2];
    const float* Wk  = (const float*)d_in[3];
    const float* Wv  = (const float*)d_in[4];
    float* out = (float*)d_out;
    float* Wqk = (float*)d_ws;                      // 16 KB scratch

    prep_wqk <<<dim3(16),    dim3(256),     0, stream>>>(Wq, Wk, Wqk);
    cag_fused<<<dim3(8192),  dim3(THREADS), 0, stream>>>(fq, fkv, Wqk, Wv, out);
}